// Round 3
// baseline (46.710 us; speedup 1.0000x reference)
//
#include <hip/hip_runtime.h>
#include <hip/hip_cooperative_groups.h>
#include <math.h>

namespace cg = cooperative_groups;

#define NN 1024
#define HH 512
#define BB 64
#define NT 256   // threads per block
#define VV 4     // elements per thread; element e = 4*t + i

__device__ __forceinline__ void ce_local(float& ka, float& va, float& kb, float& vb, bool up) {
    // ascending: want ka <= kb; swap on strict inequality only (ties keep)
    bool sw = up ? (ka > kb) : (ka < kb);
    if (sw) { float tk = ka; ka = kb; kb = tk; float tv = va; va = vb; vb = tv; }
}

__global__ __launch_bounds__(NT) void lfl_coop(const float* __restrict__ scores,
                                               const float* __restrict__ labels,
                                               float* __restrict__ out,
                                               float* __restrict__ partial) {
    __shared__ float kbuf[2][NN];   // [i*NT + t] layout (bank-friendly)
    __shared__ float vbuf[2][NN];
    __shared__ float osc_l[NN];
    __shared__ float sa_l[NN];
    __shared__ float sb_l[NN];
    __shared__ float wA[4], wB[4];

    const int b    = blockIdx.x;
    const int t    = threadIdx.x;
    const int lane = t & 63;
    const int wv   = t >> 6;

    float k[VV], v[VV];
    const float4 lb4 = *reinterpret_cast<const float4*>(&labels[b * NN + 4 * t]);
    const float4 sc4 = *reinterpret_cast<const float4*>(&scores[b * NN + 4 * t]);
    k[0] = -lb4.x; k[1] = -lb4.y; k[2] = -lb4.z; k[3] = -lb4.w;
    v[0] = sc4.x;  v[1] = sc4.y;  v[2] = sc4.z;  v[3] = sc4.w;

    auto shfl_ce = [&](int ts, bool up) {
        bool lower = ((t & ts) == 0);
        bool cond  = (up == lower);
        #pragma unroll
        for (int i = 0; i < VV; ++i) {
            float kp = __shfl_xor(k[i], ts);
            float vp = __shfl_xor(v[i], ts);
            bool take = cond ? (kp < k[i]) : (kp > k[i]);
            if (take) { k[i] = kp; v[i] = vp; }
        }
    };
    auto lds_ex = [&](int ts, bool up, int pb) {
        #pragma unroll
        for (int i = 0; i < VV; ++i) { kbuf[pb][i * NT + t] = k[i]; vbuf[pb][i * NT + t] = v[i]; }
        __syncthreads();
        int p = t ^ ts;
        bool lower = ((t & ts) == 0);
        bool cond  = (up == lower);
        #pragma unroll
        for (int i = 0; i < VV; ++i) {
            float kp = kbuf[pb][i * NT + p];
            float vp = vbuf[pb][i * NT + p];
            bool take = cond ? (kp < k[i]) : (kp > k[i]);
            if (take) { k[i] = kp; v[i] = vp; }
        }
    };
    auto intra2 = [&](bool up) {   // element strides 2 then 1 within thread
        ce_local(k[0], v[0], k[2], v[2], up);
        ce_local(k[1], v[1], k[3], v[3], up);
        ce_local(k[0], v[0], k[1], v[1], up);
        ce_local(k[2], v[2], k[3], v[3], up);
    };

    // ---- Bitonic sort, ascending on k = -label ----
    // size 2: pair (0,1) asc, (2,3) desc
    ce_local(k[0], v[0], k[1], v[1], true);
    ce_local(k[2], v[2], k[3], v[3], false);
    // size 4: strides 2,1 intra-thread
    intra2((t & 1) == 0);
    // sizes 8..256: shuffles + intra  (size4 = size/4 = 2..64)
    #pragma unroll
    for (unsigned size4 = 2; size4 <= 64; size4 <<= 1) {
        bool up = ((t & size4) == 0);
        for (unsigned ts = size4 >> 1; ts >= 1; ts >>= 1) shfl_ce((int)ts, up);
        intra2(up);
    }
    // size 512: element stride 256 -> LDS (ts=64), then shuffles, then intra
    {
        bool up = ((t & 128) == 0);
        lds_ex(64, up, 0);
        for (unsigned ts = 32; ts >= 1; ts >>= 1) shfl_ce((int)ts, up);
        intra2(up);
    }
    // size 1024: strides 512,256 -> LDS, then shuffles, then intra (up = true)
    {
        lds_ex(128, true, 1);
        lds_ex(64,  true, 0);
        for (unsigned ts = 32; ts >= 1; ts >>= 1) shfl_ce((int)ts, true);
        intra2(true);
    }
    // thread t holds sorted elements 4t..4t+3 (osc = v)

    // ---- Suffix scans of e^{osc}, e^{-osc} ----
    float la[VV], lbv[VV];
    #pragma unroll
    for (int i = 0; i < VV; ++i) { la[i] = __expf(v[i]); lbv[i] = __expf(-v[i]); }
    float La[VV], Lb[VV];
    La[3] = la[3];  Lb[3] = lbv[3];
    La[2] = la[2] + La[3];  Lb[2] = lbv[2] + Lb[3];
    La[1] = la[1] + La[2];  Lb[1] = lbv[1] + Lb[2];
    La[0] = la[0] + La[1];  Lb[0] = lbv[0] + Lb[1];
    float Ta = La[0], Tb = Lb[0];
    float Sa = Ta,   Sb = Tb;
    #pragma unroll
    for (int d = 1; d < 64; d <<= 1) {
        float xa = __shfl_down(Sa, d);
        float xb = __shfl_down(Sb, d);
        if (lane + d < 64) { Sa += xa; Sb += xb; }
    }
    if (lane == 0) { wA[wv] = Sa; wB[wv] = Sb; }   // wave totals
    __syncthreads();
    float addA = 0.f, addB = 0.f;
    for (int w2 = wv + 1; w2 < 4; ++w2) { addA += wA[w2]; addB += wB[w2]; }
    float baseA = (Sa - Ta) + addA;   // strict suffix of threads above
    float baseB = (Sb - Tb) + addB;

    // ---- Publish per-element arrays ----
    #pragma unroll
    for (int i = 0; i < VV; ++i) {
        int e = 4 * t + i;
        osc_l[e] = v[i];
        sa_l[e]  = baseA + La[i];
        sb_l[e]  = baseB + Lb[i];
    }
    __syncthreads();

    // ---- Terms: j = 2t, 2t+1 ----
    float sa513 = sa_l[513];
    float acc = 0.f;
    #pragma unroll
    for (int q = 0; q < 2; ++q) {
        int j = 2 * t + q;
        float P = sa_l[j] - sa513;               // sum_{n=j}^{512} e^{osc[n]}
        float T = sb_l[511 + j];                 // sum_{k=511+j}^{1023} e^{-osc[k]}
        float denom = P * T - (j == 0 ? 2.0f : (j == 1 ? 1.0f : 0.0f));
        acc += (osc_l[j] - osc_l[NN - 1 - j]) - __logf(denom);
    }

    // ---- Block reduce -> partial[b] ----
    #pragma unroll
    for (int off = 32; off > 0; off >>= 1) acc += __shfl_down(acc, off);
    if (lane == 0) wA[wv] = acc;    // wA reads above all precede the publish barrier
    __syncthreads();
    if (t == 0) partial[b] = wA[0] + wA[1] + wA[2] + wA[3];

    // ---- Grid-wide reduce ----
    cg::this_grid().sync();
    if (b == 0 && t < 64) {
        float x = partial[t];
        #pragma unroll
        for (int off = 32; off > 0; off >>= 1) x += __shfl_down(x, off);
        if (t == 0) out[0] = -x / (float)BB;
    }
}

extern "C" void kernel_launch(void* const* d_in, const int* in_sizes, int n_in,
                              void* d_out, int out_size, void* d_ws, size_t ws_size,
                              hipStream_t stream) {
    const float* scores = (const float*)d_in[0];
    const float* labels = (const float*)d_in[1];
    float* out = (float*)d_out;
    float* partial = (float*)d_ws;

    void* args[] = { (void*)&scores, (void*)&labels, (void*)&out, (void*)&partial };
    hipLaunchCooperativeKernel(reinterpret_cast<void*>(lfl_coop),
                               dim3(BB), dim3(NT), args, 0, stream);
}

// Round 4
// 23.322 us; speedup vs baseline: 2.0028x; 2.0028x over previous
//
#include <hip/hip_runtime.h>
#include <math.h>

#define NN 1024
#define HH 512
#define BB 64
#define NT 256   // threads per block
#define VV 4     // elements per thread; element e = 4*t + i

__device__ __forceinline__ void ce_local(float& ka, float& va, float& kb, float& vb, bool up) {
    // ascending: want ka <= kb; swap on strict inequality only (ties keep)
    bool sw = up ? (ka > kb) : (ka < kb);
    if (sw) { float tk = ka; ka = kb; kb = tk; float tv = va; va = vb; vb = tv; }
}

__global__ __launch_bounds__(NT) void lfl_fused(const float* __restrict__ scores,
                                                const float* __restrict__ labels,
                                                float* __restrict__ out) {
    __shared__ float kbuf[2][NN];   // [i*NT + t] layout
    __shared__ float vbuf[2][NN];
    __shared__ float osc_l[NN];
    __shared__ float sa_l[NN];
    __shared__ float sb_l[NN];
    __shared__ float wA[4], wB[4];

    const int b    = blockIdx.x;
    const int t    = threadIdx.x;
    const int lane = t & 63;
    const int wv   = t >> 6;

    float k[VV], v[VV];
    const float4 lb4 = *reinterpret_cast<const float4*>(&labels[b * NN + 4 * t]);
    const float4 sc4 = *reinterpret_cast<const float4*>(&scores[b * NN + 4 * t]);
    k[0] = -lb4.x; k[1] = -lb4.y; k[2] = -lb4.z; k[3] = -lb4.w;
    v[0] = sc4.x;  v[1] = sc4.y;  v[2] = sc4.z;  v[3] = sc4.w;

    auto shfl_ce = [&](int ts, bool up) {
        bool lower = ((t & ts) == 0);
        bool cond  = (up == lower);
        #pragma unroll
        for (int i = 0; i < VV; ++i) {
            float kp = __shfl_xor(k[i], ts);
            float vp = __shfl_xor(v[i], ts);
            bool take = cond ? (kp < k[i]) : (kp > k[i]);
            if (take) { k[i] = kp; v[i] = vp; }
        }
    };
    auto lds_ex = [&](int ts, bool up, int pb) {
        #pragma unroll
        for (int i = 0; i < VV; ++i) { kbuf[pb][i * NT + t] = k[i]; vbuf[pb][i * NT + t] = v[i]; }
        __syncthreads();
        int p = t ^ ts;
        bool lower = ((t & ts) == 0);
        bool cond  = (up == lower);
        #pragma unroll
        for (int i = 0; i < VV; ++i) {
            float kp = kbuf[pb][i * NT + p];
            float vp = vbuf[pb][i * NT + p];
            bool take = cond ? (kp < k[i]) : (kp > k[i]);
            if (take) { k[i] = kp; v[i] = vp; }
        }
    };
    auto intra2 = [&](bool up) {   // element strides 2 then 1 within thread
        ce_local(k[0], v[0], k[2], v[2], up);
        ce_local(k[1], v[1], k[3], v[3], up);
        ce_local(k[0], v[0], k[1], v[1], up);
        ce_local(k[2], v[2], k[3], v[3], up);
    };

    // ---- Bitonic sort, ascending on k = -label ----
    ce_local(k[0], v[0], k[1], v[1], true);
    ce_local(k[2], v[2], k[3], v[3], false);
    intra2((t & 1) == 0);
    #pragma unroll
    for (unsigned size4 = 2; size4 <= 64; size4 <<= 1) {
        bool up = ((t & size4) == 0);
        for (unsigned ts = size4 >> 1; ts >= 1; ts >>= 1) shfl_ce((int)ts, up);
        intra2(up);
    }
    // size 512: element stride 256 -> LDS (thread-stride 64), rest shuffles
    {
        bool up = ((t & 128) == 0);
        lds_ex(64, up, 0);
        for (unsigned ts = 32; ts >= 1; ts >>= 1) shfl_ce((int)ts, up);
        intra2(up);
    }
    // size 1024: thread-strides 128,64 -> LDS, rest shuffles (up = true)
    {
        lds_ex(128, true, 1);
        lds_ex(64,  true, 0);
        for (unsigned ts = 32; ts >= 1; ts >>= 1) shfl_ce((int)ts, true);
        intra2(true);
    }
    // thread t holds sorted elements 4t..4t+3 (osc = v)

    // ---- Suffix scans of e^{osc}, e^{-osc} ----
    float la[VV], lbv[VV];
    #pragma unroll
    for (int i = 0; i < VV; ++i) { la[i] = __expf(v[i]); lbv[i] = __expf(-v[i]); }
    float La[VV], Lb[VV];
    La[3] = la[3];            Lb[3] = lbv[3];
    La[2] = la[2] + La[3];    Lb[2] = lbv[2] + Lb[3];
    La[1] = la[1] + La[2];    Lb[1] = lbv[1] + Lb[2];
    La[0] = la[0] + La[1];    Lb[0] = lbv[0] + Lb[1];
    float Ta = La[0], Tb = Lb[0];
    float Sa = Ta,   Sb = Tb;
    #pragma unroll
    for (int d = 1; d < 64; d <<= 1) {
        float xa = __shfl_down(Sa, d);
        float xb = __shfl_down(Sb, d);
        if (lane + d < 64) { Sa += xa; Sb += xb; }
    }
    if (lane == 0) { wA[wv] = Sa; wB[wv] = Sb; }   // wave totals
    __syncthreads();
    float addA = 0.f, addB = 0.f;
    for (int w2 = wv + 1; w2 < 4; ++w2) { addA += wA[w2]; addB += wB[w2]; }
    float baseA = (Sa - Ta) + addA;   // strict suffix of threads above mine
    float baseB = (Sb - Tb) + addB;

    // ---- Publish per-element arrays ----
    #pragma unroll
    for (int i = 0; i < VV; ++i) {
        int e = 4 * t + i;
        osc_l[e] = v[i];
        sa_l[e]  = baseA + La[i];
        sb_l[e]  = baseB + Lb[i];
    }
    __syncthreads();

    // ---- Terms: j = 2t, 2t+1 ----
    float sa513 = sa_l[513];
    float acc = 0.f;
    #pragma unroll
    for (int q = 0; q < 2; ++q) {
        int j = 2 * t + q;
        float P = sa_l[j] - sa513;               // sum_{n=j}^{512} e^{osc[n]}
        float T = sb_l[511 + j];                 // sum_{k=511+j}^{1023} e^{-osc[k]}
        float denom = P * T - (j == 0 ? 2.0f : (j == 1 ? 1.0f : 0.0f));
        acc += (osc_l[j] - osc_l[NN - 1 - j]) - __logf(denom);
    }

    // ---- Block reduce -> one atomic ----
    #pragma unroll
    for (int off = 32; off > 0; off >>= 1) acc += __shfl_down(acc, off);
    if (lane == 0) wA[wv] = acc;
    __syncthreads();
    if (t == 0) {
        float s = wA[0] + wA[1] + wA[2] + wA[3];
        atomicAdd(out, -s / (float)BB);
    }
}

extern "C" void kernel_launch(void* const* d_in, const int* in_sizes, int n_in,
                              void* d_out, int out_size, void* d_ws, size_t ws_size,
                              hipStream_t stream) {
    const float* scores = (const float*)d_in[0];
    const float* labels = (const float*)d_in[1];
    float* out = (float*)d_out;

    hipMemsetAsync(out, 0, sizeof(float), stream);
    lfl_fused<<<BB, NT, 0, stream>>>(scores, labels, out);
}

// Round 5
// 18.838 us; speedup vs baseline: 2.4795x; 1.2380x over previous
//
#include <hip/hip_runtime.h>
#include <math.h>

#define NN 1024
#define HH 512
#define BB 64
#define NT 1024   // 16 waves -> 4 waves/SIMD: latency hiding for the shuffle chains

__global__ __launch_bounds__(NT) void lfl_fused(const float* __restrict__ scores,
                                                const float* __restrict__ labels,
                                                float* __restrict__ out) {
    __shared__ float2 kv[2][NN];    // double-buffered packed (key,score): 16 KB
    __shared__ float osc_l[NN];
    __shared__ float sa_l[NN];
    __shared__ float sb_l[NN];
    __shared__ float wA[16], wB[16];

    const int b    = blockIdx.x;
    const int t    = threadIdx.x;
    const int lane = t & 63;
    const int wv   = t >> 6;

    // key = -label (ascending == descending label == argsort(-labels)), payload = score
    float k = -labels[b * NN + t];
    float v = scores[b * NN + t];

    auto shfl_ce = [&](int stride, bool up) {
        float kp = __shfl_xor(k, stride);
        float vp = __shfl_xor(v, stride);
        bool lower = ((t & stride) == 0);
        bool take  = (up == lower) ? (kp < k) : (kp > k);   // strict: ties never swap
        if (take) { k = kp; v = vp; }
    };

    int pb = 0;
    auto lds_ex = [&](int stride, bool up) {
        kv[pb][t] = make_float2(k, v);
        __syncthreads();                       // single barrier: next round uses other buffer
        float2 p = kv[pb][t ^ stride];
        bool lower = ((t & stride) == 0);
        bool take  = (up == lower) ? (p.x < k) : (p.x > k);
        if (take) { k = p.x; v = p.y; }
        pb ^= 1;
    };

    // ---- Bitonic sort, ascending on k ----
    // sizes 2..64: fully intra-wave
    #pragma unroll
    for (int size = 2; size <= 64; size <<= 1) {
        bool up = ((t & size) == 0);
        #pragma unroll
        for (int s = size >> 1; s >= 1; s >>= 1) shfl_ce(s, up);
    }
    // sizes 128..1024: strides >=64 via LDS (1 barrier each, alternating buffers)
    #pragma unroll
    for (int size = 128; size <= 1024; size <<= 1) {
        bool up = ((t & size) == 0);           // size=1024: always true
        for (int s = size >> 1; s >= 64; s >>= 1) lds_ex(s, up);
        #pragma unroll
        for (int s = 32; s >= 1; s >>= 1) shfl_ce(s, up);
    }
    // thread t holds sorted element t: osc[t] = v

    // ---- Suffix scans of e^{osc}, e^{-osc}: register wave-scan + cross-wave fixup ----
    float Sa = __expf(v);
    float Sb = __expf(-v);
    #pragma unroll
    for (int d = 1; d < 64; d <<= 1) {
        float xa = __shfl_down(Sa, d);
        float xb = __shfl_down(Sb, d);
        if (lane + d < 64) { Sa += xa; Sb += xb; }
    }
    if (lane == 0) { wA[wv] = Sa; wB[wv] = Sb; }   // lane 0 holds wave total
    __syncthreads();
    float addA = 0.f, addB = 0.f;
    for (int w = wv + 1; w < 16; ++w) { addA += wA[w]; addB += wB[w]; }
    float sa = Sa + addA;   // inclusive suffix sum of e^{osc} at index t
    float sb = Sb + addB;   // inclusive suffix sum of e^{-osc} at index t

    // ---- Publish ----
    osc_l[t] = v;
    sa_l[t]  = sa;
    sb_l[t]  = sb;
    __syncthreads();

    // ---- Per-j term (j = t < 512) ----
    float acc = 0.f;
    if (t < HH) {
        float P = sa - sa_l[513];               // sum_{n=j}^{512} e^{osc[n]}
        float T = sb_l[511 + t];                // sum_{k=511+j}^{1023} e^{-osc[k]}
        float denom = P * T - (t == 0 ? 2.0f : (t == 1 ? 1.0f : 0.0f));
        acc = (v - osc_l[NN - 1 - t]) - __logf(denom);
    }

    // ---- Block reduce -> one atomic ----
    #pragma unroll
    for (int off = 32; off > 0; off >>= 1) acc += __shfl_down(acc, off);
    if (lane == 0) wA[wv] = acc;
    __syncthreads();
    if (t == 0) {
        float s = 0.f;
        #pragma unroll
        for (int w = 0; w < 16; ++w) s += wA[w];
        atomicAdd(out, -s / (float)BB);
    }
}

extern "C" void kernel_launch(void* const* d_in, const int* in_sizes, int n_in,
                              void* d_out, int out_size, void* d_ws, size_t ws_size,
                              hipStream_t stream) {
    const float* scores = (const float*)d_in[0];
    const float* labels = (const float*)d_in[1];
    float* out = (float*)d_out;

    hipMemsetAsync(out, 0, sizeof(float), stream);
    lfl_fused<<<BB, NT, 0, stream>>>(scores, labels, out);
}

// Round 6
// 14.143 us; speedup vs baseline: 3.3027x; 1.3320x over previous
//
#include <hip/hip_runtime.h>
#include <math.h>

#define NN 1024
#define HH 512
#define BB 64
#define NT 1024   // 16 waves -> 4 waves/SIMD
#define MAGIC 0x5A5A5A5Au

__global__ __launch_bounds__(NT) void lfl_fused(const float* __restrict__ scores,
                                                const float* __restrict__ labels,
                                                float* __restrict__ out,
                                                unsigned long long* __restrict__ slots) {
    __shared__ float2 kv[2][NN];    // double-buffered packed (key,score)
    __shared__ float osc_l[NN];
    __shared__ float sa_l[NN];
    __shared__ float sb_l[NN];
    __shared__ float wA[16], wB[16];

    const int b    = blockIdx.x;
    const int t    = threadIdx.x;
    const int lane = t & 63;
    const int wv   = t >> 6;

    // key = -label (ascending == descending label == argsort(-labels)), payload = score
    float k = -labels[b * NN + t];
    float v = scores[b * NN + t];

    auto shfl_ce = [&](int stride, bool up) {
        float kp = __shfl_xor(k, stride);
        float vp = __shfl_xor(v, stride);
        bool lower = ((t & stride) == 0);
        bool take  = (up == lower) ? (kp < k) : (kp > k);   // strict: ties never swap
        if (take) { k = kp; v = vp; }
    };

    int pb = 0;
    auto lds_ex = [&](int stride, bool up) {
        kv[pb][t] = make_float2(k, v);
        __syncthreads();                       // single barrier: next round uses other buffer
        float2 p = kv[pb][t ^ stride];
        bool lower = ((t & stride) == 0);
        bool take  = (up == lower) ? (p.x < k) : (p.x > k);
        if (take) { k = p.x; v = p.y; }
        pb ^= 1;
    };

    // ---- Bitonic sort, ascending on k ----
    #pragma unroll
    for (int size = 2; size <= 64; size <<= 1) {
        bool up = ((t & size) == 0);
        #pragma unroll
        for (int s = size >> 1; s >= 1; s >>= 1) shfl_ce(s, up);
    }
    #pragma unroll
    for (int size = 128; size <= 1024; size <<= 1) {
        bool up = ((t & size) == 0);           // size=1024: always true
        for (int s = size >> 1; s >= 64; s >>= 1) lds_ex(s, up);
        #pragma unroll
        for (int s = 32; s >= 1; s >>= 1) shfl_ce(s, up);
    }
    // thread t holds sorted element t: osc[t] = v

    // ---- Suffix scans of e^{osc}, e^{-osc} ----
    float Sa = __expf(v);
    float Sb = __expf(-v);
    #pragma unroll
    for (int d = 1; d < 64; d <<= 1) {
        float xa = __shfl_down(Sa, d);
        float xb = __shfl_down(Sb, d);
        if (lane + d < 64) { Sa += xa; Sb += xb; }
    }
    if (lane == 0) { wA[wv] = Sa; wB[wv] = Sb; }
    __syncthreads();
    float addA = 0.f, addB = 0.f;
    for (int w = wv + 1; w < 16; ++w) { addA += wA[w]; addB += wB[w]; }
    float sa = Sa + addA;   // inclusive suffix sum of e^{osc} at index t
    float sb = Sb + addB;   // inclusive suffix sum of e^{-osc} at index t

    // ---- Publish ----
    osc_l[t] = v;
    sa_l[t]  = sa;
    sb_l[t]  = sb;
    __syncthreads();

    // ---- Per-j term (j = t < 512) ----
    float acc = 0.f;
    if (t < HH) {
        float P = sa - sa_l[513];               // sum_{n=j}^{512} e^{osc[n]}
        float T = sb_l[511 + t];                // sum_{k=511+j}^{1023} e^{-osc[k]}
        float denom = P * T - (t == 0 ? 2.0f : (t == 1 ? 1.0f : 0.0f));
        acc = (v - osc_l[NN - 1 - t]) - __logf(denom);
    }

    // ---- Block reduce ----
    #pragma unroll
    for (int off = 32; off > 0; off >>= 1) acc += __shfl_down(acc, off);
    if (lane == 0) wA[wv] = acc;
    __syncthreads();

    float part = 0.f;
    if (t == 0) {
        #pragma unroll
        for (int w = 0; w < 16; ++w) part += wA[w];
        if (b != 0) {
            // self-validating publish: {bits^MAGIC, bits} — poison (0xAA..) never validates
            unsigned lo = __float_as_uint(part);
            unsigned long long pk = ((unsigned long long)(lo ^ MAGIC) << 32) | (unsigned long long)lo;
            atomicExch(&slots[b], pk);          // device-scope RMW -> visible cross-XCD
        }
    }

    // ---- Block 0, wave 0: gather the other 63 partials and write out ----
    if (b == 0 && t < 64) {
        float x = (t == 0) ? part : 0.f;
        if (t > 0) {
            unsigned long long pk;
            do {
                pk = atomicAdd(&slots[t], 0ULL);    // device-scope atomic read
            } while ((unsigned)(pk >> 32) != ((unsigned)pk ^ MAGIC));
            x = __uint_as_float((unsigned)pk);
        }
        #pragma unroll
        for (int off = 32; off > 0; off >>= 1) x += __shfl_down(x, off);
        if (t == 0) out[0] = -x / (float)BB;
    }
}

extern "C" void kernel_launch(void* const* d_in, const int* in_sizes, int n_in,
                              void* d_out, int out_size, void* d_ws, size_t ws_size,
                              hipStream_t stream) {
    const float* scores = (const float*)d_in[0];
    const float* labels = (const float*)d_in[1];
    float* out = (float*)d_out;
    unsigned long long* slots = (unsigned long long*)d_ws;

    lfl_fused<<<BB, NT, 0, stream>>>(scores, labels, out, slots);
}